// Round 3
// baseline (18183.258 us; speedup 1.0000x reference)
//
#include <hip/hip_runtime.h>
#include <stdint.h>

// Problem dims
#define Md 50
#define Kd 50
#define Vd 200
#define Ad 64
#define Bd 512
#define Sd 1024

__device__ __forceinline__ float fast_tanh(float x) {
    float e = __expf(2.f * x);
    return 1.f - 2.f / (e + 1.f);
}

__device__ __forceinline__ float sigmoidf_(float x) {
    return 1.f / (1.f + __expf(-x));
}

// =====================================================================
// Kernel 1: precompute all softmax weights (depends only on q).
// =====================================================================
__global__ __launch_bounds__(256)
void wpre_kernel(const float* __restrict__ q_in,
                 const float* __restrict__ key_in,
                 const float* __restrict__ Wc_in,
                 const float* __restrict__ bc_in,
                 float* __restrict__ w_out)
{
    __shared__ float sWc[Kd * 51];
    __shared__ float sKey[Md * 51];
    __shared__ float sbc[Kd];
    __shared__ __align__(16) float sbuf[4][64];

    const int tid = threadIdx.x;
    for (int idx = tid; idx < Kd * Kd; idx += 256) {
        int i = idx / Kd, j = idx % Kd;
        sWc[i * 51 + j]  = Wc_in[idx];
        sKey[i * 51 + j] = key_in[idx];
    }
    if (tid < Kd) sbc[tid] = bc_in[tid];
    __syncthreads();

    const int wv = tid >> 6, ln = tid & 63;
    const int gw = blockIdx.x * 4 + wv;

    for (int r = 0; r < 64; ++r) {
        const size_t row = (size_t)gw * 64 + r;
        float qv = 0.f;
        if (ln < Kd) qv = q_in[row * Kd + ln];
        sbuf[wv][ln] = qv;
        __syncthreads();

        float ck = 0.f;
        if (ln < Kd) {
            const float4* qp = (const float4*)sbuf[wv];
            float acc = sbc[ln];
            #pragma unroll
            for (int c = 0; c < 12; ++c) {
                float4 x = qp[c];
                acc = fmaf(x.x, sWc[ln * 51 + 4 * c + 0], acc);
                acc = fmaf(x.y, sWc[ln * 51 + 4 * c + 1], acc);
                acc = fmaf(x.z, sWc[ln * 51 + 4 * c + 2], acc);
                acc = fmaf(x.w, sWc[ln * 51 + 4 * c + 3], acc);
            }
            float2 x2 = *(const float2*)&sbuf[wv][48];
            acc = fmaf(x2.x, sWc[ln * 51 + 48], acc);
            acc = fmaf(x2.y, sWc[ln * 51 + 49], acc);
            ck = fast_tanh(acc);
        }
        __syncthreads();
        sbuf[wv][ln] = ck;
        __syncthreads();

        float lg = -1e30f;
        if (ln < Md) {
            const float4* cp = (const float4*)sbuf[wv];
            float acc = 0.f;
            #pragma unroll
            for (int c = 0; c < 12; ++c) {
                float4 x = cp[c];
                acc = fmaf(x.x, sKey[ln * 51 + 4 * c + 0], acc);
                acc = fmaf(x.y, sKey[ln * 51 + 4 * c + 1], acc);
                acc = fmaf(x.z, sKey[ln * 51 + 4 * c + 2], acc);
                acc = fmaf(x.w, sKey[ln * 51 + 4 * c + 3], acc);
            }
            float2 x2 = *(const float2*)&sbuf[wv][48];
            acc = fmaf(x2.x, sKey[ln * 51 + 48], acc);
            acc = fmaf(x2.y, sKey[ln * 51 + 49], acc);
            lg = acc;
        }
        float mx = lg;
        #pragma unroll
        for (int off = 32; off > 0; off >>= 1)
            mx = fmaxf(mx, __shfl_xor(mx, off));
        float e = (ln < Md) ? __expf(lg - mx) : 0.f;
        float sm = e;
        #pragma unroll
        for (int off = 32; off > 0; off >>= 1)
            sm += __shfl_xor(sm, off);
        if (ln < Md) w_out[row * Md + ln] = e / sm;
        __syncthreads();
    }
}

// =====================================================================
// Kernel 2: sequential scan. 256 blocks x 1024 threads (16 waves/CU).
// Phases per step (4 barriers):
//   P3a: rc partials (Wr chunks in regs, wave-uniform rv reads)
//   P3b: rc finalize -> swi ; w(t+1) commit
//   P1 : erase/add dots (We/Wa 32-k chunks in regs, quad reduce)
//   P2 : mem update + rv(t+1), wave-uniform w reads ; a(t+1) commit
// Global prefetches issued at top of P1, consumed 2-3 barriers later.
// =====================================================================
__global__ __launch_bounds__(1024)
void agm_kernel(const float* __restrict__ a_in,    // (B,S,A)
                const float* __restrict__ mem_in,  // (B,M,V)
                const float* __restrict__ Wr_in,   // (A,V)
                const float* __restrict__ br_in,   // (A)
                const float* __restrict__ We_in,   // (V,2A)
                const float* __restrict__ be_in,   // (V)
                const float* __restrict__ Wa_in,   // (V,2A)
                const float* __restrict__ ba_in,   // (V)
                const float* __restrict__ w_in,    // (B,S,M) precomputed
                float* __restrict__ rc_out,        // (B,S,A)
                float* __restrict__ mem_out)       // (B,M,V)
{
    __shared__ __align__(16) float swi[2][128];       // [bat][ a_t(64) | rc(64) ]
    __shared__ __align__(16) float sw_[2][2][2][28];  // [par][bat][mh][28]
    __shared__ __align__(16) float srcvP2[4][224];    // [mh*2+bat][c*28+j]
    __shared__ __align__(16) float eradI2[4][256];    // [q][v]: ev0,av0,ev1,av1
    __shared__ __align__(16) float spr[16][2][64];    // [wave][bat][a]
    __shared__ float sbr[Ad];
    __shared__ float sbe[Vd];
    __shared__ float sba[Vd];

    const int tid = threadIdx.x;
    const int blk = blockIdx.x;
    const int wv  = tid >> 6;
    const int ln  = tid & 63;

    // ---- per-phase roles ----
    const int r1 = tid >> 2, q1 = tid & 3;                // P1: row, k-quarter
    const int p2mh = wv >> 3, p2bt = (wv >> 2) & 1;       // P2 (wave-uniform)
    const int p2v  = ((wv & 3) << 6) | ln;
    const int p2b  = blk * 2 + p2bt;
    const int c3 = wv & 7, h3 = wv >> 3;                  // P3a

    // ---- register-resident We/Wa 32-k chunks ----
    float WC[64];
    if (r1 < Vd) {
        const float4* wep = (const float4*)(We_in + (size_t)r1 * 128 + q1 * 32);
        const float4* wap = (const float4*)(Wa_in + (size_t)r1 * 128 + q1 * 32);
        #pragma unroll
        for (int c = 0; c < 8; ++c) {
            float4 u = wep[c];
            WC[4*c+0] = u.x; WC[4*c+1] = u.y; WC[4*c+2] = u.z; WC[4*c+3] = u.w;
        }
        #pragma unroll
        for (int c = 0; c < 8; ++c) {
            float4 u = wap[c];
            WC[32+4*c+0] = u.x; WC[32+4*c+1] = u.y; WC[32+4*c+2] = u.z; WC[32+4*c+3] = u.w;
        }
    } else {
        #pragma unroll
        for (int j = 0; j < 64; ++j) WC[j] = 0.f;
    }

    // ---- register-resident Wr sub-chunks ----
    float WrS[13];
    {
        const int nj = h3 ? 12 : 13;
        const int vb = c3 * 25 + h3 * 13;
        #pragma unroll
        for (int j = 0; j < 13; ++j)
            WrS[j] = (j < nj) ? Wr_in[(size_t)ln * Vd + vb + j] : 0.f;
    }

    // ---- register-resident memory half-columns ----
    float memcol[25];
    if (p2v < Vd) {
        #pragma unroll
        for (int j = 0; j < 25; ++j)
            memcol[j] = mem_in[(size_t)p2b * Md * Vd + (p2mh * 25 + j) * Vd + p2v];
    } else {
        #pragma unroll
        for (int j = 0; j < 25; ++j) memcol[j] = 0.f;
    }
    const int p2off = (p2v / 25) * 28 + (p2v % 25);
    const int p2pl  = p2mh * 2 + p2bt;

    // ---- loader roles ----
    const bool isAld = (tid >= 896);                      // a(t) loader/committer
    const int  abt = wv & 1;
    const float* aload = a_in + (size_t)(blk * 2 + abt) * Sd * Ad + ln;
    const bool isWld = (tid >= 256 && tid < 356);         // w(t) loader/committer
    const int  wub = isWld ? (tid - 256) : 0;
    const int  wbt = wub / 50;
    const int  wm  = wub - wbt * 50;
    const float* wload = w_in + (size_t)(blk * 2 + wbt) * Sd * Md + wm;
    float* wcom = &sw_[0][wbt][wm / 25][wm % 25];

    // ---- one-time LDS staging ----
    if (tid < 200) {
        int s = tid / 100, rst = tid % 100;
        int bt = rst / 50, m = rst % 50;
        sw_[s][bt][m / 25][m % 25] = w_in[((size_t)(blk * 2 + bt) * Sd + s) * Md + m];
    } else if (tid < 328) {
        int u = tid - 200;
        swi[u >> 6][u & 63] = a_in[(size_t)(blk * 2 + (u >> 6)) * Sd * Ad + (u & 63)];
    } else if (tid < 392) {
        sbr[tid - 328] = br_in[tid - 328];
    } else if (tid < 592) {
        sbe[tid - 392] = be_in[tid - 392];
    } else if (tid < 792) {
        sba[tid - 592] = ba_in[tid - 592];
    }
    float areg = 0.f, anext = 0.f, wreg = 0.f, wnext = 0.f, rcval = 0.f;
    if (isAld) areg = aload[(size_t)1 * Ad];              // a(1)
    __syncthreads();

    // ---- prologue: rv(0) = w(0) . memcol ----
    if (p2v < Vd) {
        const float4* wp = (const float4*)&sw_[0][p2bt][p2mh][0];
        float rv = 0.f;
        #pragma unroll
        for (int c = 0; c < 6; ++c) {
            float4 w4 = wp[c];
            rv = fmaf(w4.x, memcol[4*c+0], rv);
            rv = fmaf(w4.y, memcol[4*c+1], rv);
            rv = fmaf(w4.z, memcol[4*c+2], rv);
            rv = fmaf(w4.w, memcol[4*c+3], rv);
        }
        rv = fmaf(sw_[0][p2bt][p2mh][24], memcol[24], rv);
        srcvP2[p2pl][p2off] = rv;
    }
    __syncthreads();

    // ---- main scan ----
    for (int t = 0; t < Sd; ++t) {
        // ===== P3a: rc partials =====
        {
            const int cb = c3 * 28 + h3 * 12;
            const float* b00 = &srcvP2[0][cb];
            const float* b01 = &srcvP2[1][cb];
            const float* b10 = &srcvP2[2][cb];
            const float* b11 = &srcvP2[3][cb];
            float a0 = 0.f, a1 = 0.f;
            if (h3 == 0) {
                #pragma unroll
                for (int c = 0; c < 3; ++c) {
                    float4 u0 = *(const float4*)(b00 + 4*c);
                    float4 u2 = *(const float4*)(b10 + 4*c);
                    float4 u1 = *(const float4*)(b01 + 4*c);
                    float4 u3 = *(const float4*)(b11 + 4*c);
                    a0 = fmaf(u0.x + u2.x, WrS[4*c+0], a0);
                    a0 = fmaf(u0.y + u2.y, WrS[4*c+1], a0);
                    a0 = fmaf(u0.z + u2.z, WrS[4*c+2], a0);
                    a0 = fmaf(u0.w + u2.w, WrS[4*c+3], a0);
                    a1 = fmaf(u1.x + u3.x, WrS[4*c+0], a1);
                    a1 = fmaf(u1.y + u3.y, WrS[4*c+1], a1);
                    a1 = fmaf(u1.z + u3.z, WrS[4*c+2], a1);
                    a1 = fmaf(u1.w + u3.w, WrS[4*c+3], a1);
                }
                a0 = fmaf(b00[12] + b10[12], WrS[12], a0);
                a1 = fmaf(b01[12] + b11[12], WrS[12], a1);
            } else {
                float4 u0 = *(const float4*)(b00);
                float4 u2 = *(const float4*)(b10);
                float4 u1 = *(const float4*)(b01);
                float4 u3 = *(const float4*)(b11);
                a0 = fmaf(u0.y + u2.y, WrS[0], a0);
                a0 = fmaf(u0.z + u2.z, WrS[1], a0);
                a0 = fmaf(u0.w + u2.w, WrS[2], a0);
                a1 = fmaf(u1.y + u3.y, WrS[0], a1);
                a1 = fmaf(u1.z + u3.z, WrS[1], a1);
                a1 = fmaf(u1.w + u3.w, WrS[2], a1);
                #pragma unroll
                for (int c = 0; c < 2; ++c) {
                    u0 = *(const float4*)(b00 + 4 + 4*c);
                    u2 = *(const float4*)(b10 + 4 + 4*c);
                    u1 = *(const float4*)(b01 + 4 + 4*c);
                    u3 = *(const float4*)(b11 + 4 + 4*c);
                    a0 = fmaf(u0.x + u2.x, WrS[3+4*c+0], a0);
                    a0 = fmaf(u0.y + u2.y, WrS[3+4*c+1], a0);
                    a0 = fmaf(u0.z + u2.z, WrS[3+4*c+2], a0);
                    a0 = fmaf(u0.w + u2.w, WrS[3+4*c+3], a0);
                    a1 = fmaf(u1.x + u3.x, WrS[3+4*c+0], a1);
                    a1 = fmaf(u1.y + u3.y, WrS[3+4*c+1], a1);
                    a1 = fmaf(u1.z + u3.z, WrS[3+4*c+2], a1);
                    a1 = fmaf(u1.w + u3.w, WrS[3+4*c+3], a1);
                }
                u0 = *(const float4*)(b00 + 12);
                u2 = *(const float4*)(b10 + 12);
                u1 = *(const float4*)(b01 + 12);
                u3 = *(const float4*)(b11 + 12);
                a0 = fmaf(u0.x + u2.x, WrS[11], a0);
                a1 = fmaf(u1.x + u3.x, WrS[11], a1);
            }
            spr[wv][0][ln] = a0;
            spr[wv][1][ln] = a1;
        }
        __syncthreads();  // B3a

        // ===== P3b: rc finalize + w(t+1) commit =====
        if (tid < 128) {
            const int ra = tid & 63, rbt = tid >> 6;
            float s = sbr[ra];
            #pragma unroll
            for (int w = 0; w < 16; ++w) s += spr[w][rbt][ra];
            swi[rbt][64 + ra] = s;
            rcval = s;
        }
        if (isWld && t >= 1 && t < Sd - 1)
            wcom[((t + 1) & 1) * 112] = wreg;   // w(t+1) -> slot (t+1)&1
        __syncthreads();  // B3b

        if (t == Sd - 1) break;

        // ===== P1: erase/add dots (+ early prefetch issues) =====
        if (tid < 128)
            rc_out[((size_t)(blk * 2 + (tid >> 6)) * Sd + t) * Ad + (tid & 63)] = rcval;
        if (isWld && t + 2 < Sd) wnext = wload[(size_t)(t + 2) * Md];
        if (isAld && t + 2 < Sd) anext = aload[(size_t)(t + 2) * Ad];
        if (r1 < Vd) {
            float pe0 = 0.f, po0 = 0.f, pe1 = 0.f, po1 = 0.f;
            const float4* xap = (const float4*)&swi[0][q1 * 32];
            const float4* xbp = (const float4*)&swi[1][q1 * 32];
            #pragma unroll
            for (int c = 0; c < 8; ++c) {
                float4 x = xap[c];
                pe0 = fmaf(x.x, WC[4*c+0], pe0);
                pe0 = fmaf(x.y, WC[4*c+1], pe0);
                pe0 = fmaf(x.z, WC[4*c+2], pe0);
                pe0 = fmaf(x.w, WC[4*c+3], pe0);
                po0 = fmaf(x.x, WC[32+4*c+0], po0);
                po0 = fmaf(x.y, WC[32+4*c+1], po0);
                po0 = fmaf(x.z, WC[32+4*c+2], po0);
                po0 = fmaf(x.w, WC[32+4*c+3], po0);
            }
            #pragma unroll
            for (int c = 0; c < 8; ++c) {
                float4 x = xbp[c];
                pe1 = fmaf(x.x, WC[4*c+0], pe1);
                pe1 = fmaf(x.y, WC[4*c+1], pe1);
                pe1 = fmaf(x.z, WC[4*c+2], pe1);
                pe1 = fmaf(x.w, WC[4*c+3], pe1);
                po1 = fmaf(x.x, WC[32+4*c+0], po1);
                po1 = fmaf(x.y, WC[32+4*c+1], po1);
                po1 = fmaf(x.z, WC[32+4*c+2], po1);
                po1 = fmaf(x.w, WC[32+4*c+3], po1);
            }
            pe0 += __shfl_xor(pe0, 1); pe0 += __shfl_xor(pe0, 2);
            po0 += __shfl_xor(po0, 1); po0 += __shfl_xor(po0, 2);
            pe1 += __shfl_xor(pe1, 1); pe1 += __shfl_xor(pe1, 2);
            po1 += __shfl_xor(po1, 1); po1 += __shfl_xor(po1, 2);
            const float pre = (q1 & 2) ? pe1 : pe0;
            const float pod = (q1 & 2) ? po1 : po0;
            const float lin = (q1 & 1) ? (pod + sba[r1]) : (pre + sbe[r1]);
            const float sg  = sigmoidf_((q1 & 1) ? (lin + lin) : lin);
            eradI2[q1][r1] = (q1 & 1) ? fmaf(2.f, sg, -1.f) : sg;
        }
        __syncthreads();  // B1

        // ===== P2: mem update + rv(t+1) ; a(t+1) commit =====
        if (p2v < Vd) {
            const float ev = eradI2[2 * p2bt][p2v];
            const float av = eradI2[2 * p2bt + 1][p2v];
            const float4* w0p = (const float4*)&sw_[t & 1][p2bt][p2mh][0];
            const float4* w1p = (const float4*)&sw_[(t + 1) & 1][p2bt][p2mh][0];
            float rv = 0.f;
            #pragma unroll
            for (int c = 0; c < 6; ++c) {
                float4 wa = w0p[c];
                float4 wb = w1p[c];
                { float mc = memcol[4*c+0]; mc = fmaf(wa.x, fmaf(-ev, mc, av), mc); memcol[4*c+0] = mc; rv = fmaf(wb.x, mc, rv); }
                { float mc = memcol[4*c+1]; mc = fmaf(wa.y, fmaf(-ev, mc, av), mc); memcol[4*c+1] = mc; rv = fmaf(wb.y, mc, rv); }
                { float mc = memcol[4*c+2]; mc = fmaf(wa.z, fmaf(-ev, mc, av), mc); memcol[4*c+2] = mc; rv = fmaf(wb.z, mc, rv); }
                { float mc = memcol[4*c+3]; mc = fmaf(wa.w, fmaf(-ev, mc, av), mc); memcol[4*c+3] = mc; rv = fmaf(wb.w, mc, rv); }
            }
            {
                float wa = ((const float*)w0p)[24];
                float wb = ((const float*)w1p)[24];
                float mc = memcol[24]; mc = fmaf(wa, fmaf(-ev, mc, av), mc); memcol[24] = mc; rv = fmaf(wb, mc, rv);
            }
            srcvP2[p2pl][p2off] = rv;
        }
        if (isAld) {
            swi[abt][ln] = areg;   // commit a(t+1)
            areg = anext;
        }
        if (isWld) wreg = wnext;
        __syncthreads();  // B2
    }

    // rc(Sd-1) store (loop broke before its P1-region store)
    if (tid < 128)
        rc_out[((size_t)(blk * 2 + (tid >> 6)) * Sd + (Sd - 1)) * Ad + (tid & 63)] = rcval;

    // ---- final memory store ----
    if (p2v < Vd) {
        #pragma unroll
        for (int j = 0; j < 25; ++j)
            mem_out[(size_t)p2b * Md * Vd + (p2mh * 25 + j) * Vd + p2v] = memcol[j];
    }
}

extern "C" void kernel_launch(void* const* d_in, const int* in_sizes, int n_in,
                              void* d_out, int out_size, void* d_ws, size_t ws_size,
                              hipStream_t stream) {
    const float* q   = (const float*)d_in[0];
    const float* a   = (const float*)d_in[1];
    const float* mem = (const float*)d_in[2];
    const float* key = (const float*)d_in[3];
    const float* Wc  = (const float*)d_in[4];
    const float* bc  = (const float*)d_in[5];
    const float* Wr  = (const float*)d_in[6];
    const float* br  = (const float*)d_in[7];
    const float* We  = (const float*)d_in[8];
    const float* be  = (const float*)d_in[9];
    const float* Wa  = (const float*)d_in[10];
    const float* ba  = (const float*)d_in[11];

    float* out = (float*)d_out;
    float* rc_out  = out;                                   // (B,S,A)
    float* mem_out = rc_out + (size_t)Bd * Sd * Ad;         // (B,M,V)
    float* w_out   = mem_out + (size_t)Bd * Md * Vd;        // (B,S,M)

    // Phase 1: fully parallel softmax-weight precompute (writes w_out).
    hipLaunchKernelGGL(wpre_kernel, dim3(2048), dim3(256), 0, stream,
                       q, key, Wc, bc, w_out);
    // Phase 2: sequential scan consuming w_out.
    hipLaunchKernelGGL(agm_kernel, dim3(256), dim3(1024), 0, stream,
                       a, mem, Wr, br, We, be, Wa, ba, w_out,
                       rc_out, mem_out);
}